// Round 1
// baseline (273.201 us; speedup 1.0000x reference)
//
#include <hip/hip_runtime.h>

// SeriesDecompEMA: res = x - ma, ma = EMA(x, alpha) per (b, c) sequence over T.
// ma[t] = beta*ma[t-1] + alpha*x[t], ma[0] = x[0], beta = 1-alpha.
//
// FUSED single-kernel chunked scan (J=16 chunks of L=45):
//   block = 512 threads = (j in [0,16)) x (c_local in [0,32)), grid = (C/32) x B.
//   Phase 1: each thread loads its 45 x-values into REGISTERS (fully unrolled,
//            static indices -> VGPRs) and computes the chunk-local partial s_j.
//   Phase 2: s_j -> LDS [16][33], __syncthreads, carry E_j = Horner over k<j
//            with betaL = beta^L (identical arithmetic to the 2-kernel version).
//   Phase 3: replay the chunk from registers, seeded with E_j; write ma and res.
//
// vs previous 2-kernel version: x is fetched from HBM ONCE instead of twice,
// the 2 MB global `s` round-trip disappears, and there is a single launch with
// no inter-kernel drain. Ideal traffic: 94.4 MB read + 188.7 MB write.

constexpr int kB  = 64;
constexpr int kT  = 720;
constexpr int kC  = 512;
constexpr int kJ  = 16;          // chunks per sequence
constexpr int kL  = 45;          // chunk length; kJ*kL == kT
constexpr int kCT = 32;          // channels per block tile
constexpr int kBlockThreads = kJ * kCT;   // 512

__global__ __launch_bounds__(kBlockThreads) void ema_fused(
        const float* __restrict__ x,
        const float* __restrict__ alphap,
        float* __restrict__ res,
        float* __restrict__ ma) {
    const int tid = threadIdx.x;
    const int cl  = tid & (kCT - 1);      // channel within tile
    const int j   = tid >> 5;             // chunk index, wave = 2 consecutive j
    const int ct  = blockIdx.x;           // channel tile (16)
    const int b   = blockIdx.y;           // batch (64)
    const int c   = ct * kCT + cl;

    const float alpha = alphap[0];
    const float beta  = 1.0f - alpha;

    const size_t base = (size_t)(b * kT + j * kL) * kC + c;
    const float* xp = x + base;

    // Phase 1: load chunk into registers (static indexing -> stays in VGPRs),
    // 45 independent loads issue back-to-back: deep MLP per wave.
    float xv[kL];
    #pragma unroll
    for (int i = 0; i < kL; ++i)
        xv[i] = xp[(size_t)i * kC];

    // chunk-local partial EMA final value (seed 0); global element 0 has weight 1
    float p = ((j == 0) ? 1.0f : alpha) * xv[0];
    #pragma unroll
    for (int i = 1; i < kL; ++i)
        p = fmaf(beta, p, alpha * xv[i]);

    // Phase 2: block-local scan over j via LDS.
    __shared__ float sl[kJ][kCT + 1];     // +1 pad: conflict-free columns
    sl[j][cl] = p;
    __syncthreads();

    const float betaL = powf(beta, (float)kL);   // carry decay across one chunk
    // E_j = sum_{k<j} s_k * betaL^{j-1-k}  (Horner ascending k) — identical
    // arithmetic order to the previous passing kernel.
    float E = 0.0f;
    for (int k = 0; k < j; ++k)
        E = fmaf(E, betaL, sl[k][cl]);

    // Phase 3: replay chunk from registers, write outputs.
    float* __restrict__ rp = res + base;
    float* __restrict__ mp = ma  + base;
    float e = E;
    #pragma unroll
    for (int i = 0; i < kL; ++i) {
        const float xi = xv[i];
        const float w  = (j == 0 && i == 0) ? 1.0f : alpha;
        e = fmaf(beta, e, w * xi);        // j==0,i==0: E=0 -> e = x[0] exactly
        mp[(size_t)i * kC] = e;
        rp[(size_t)i * kC] = xi - e;
    }
}

extern "C" void kernel_launch(void* const* d_in, const int* in_sizes, int n_in,
                              void* d_out, int out_size, void* d_ws, size_t ws_size,
                              hipStream_t stream) {
    const float* x      = (const float*)d_in[0];
    const float* alphap = (const float*)d_in[1];
    float* res = (float*)d_out;                       // outputs concatenated: res then ma
    float* ma  = res + (size_t)kB * kT * kC;
    (void)d_ws; (void)ws_size;

    dim3 grid(kC / kCT, kB);                          // 16 x 64 = 1024 blocks
    ema_fused<<<grid, kBlockThreads, 0, stream>>>(x, alphap, res, ma);
}